// Round 5
// baseline (190.788 us; speedup 1.0000x reference)
//
#include <hip/hip_runtime.h>

// MACE body-3, round 4b: ONE kernel. U3/U2 read raw (contiguous-in-k per oa
// column == B-fragment shape for 32x32x16 f16 MFMA; cvt_pkrtz in-kernel).
// Block = 2 atoms, 384 threads = 6 waves = (atom x 3 n-tiles), 512 blocks,
// LDS 52224B -> 3 blocks/CU.

typedef __attribute__((ext_vector_type(8)))  _Float16 f16x8;
typedef __attribute__((ext_vector_type(4)))  _Float16 f16x4;
typedef __attribute__((ext_vector_type(2)))  __fp16   hf16x2;   // cvt_pkrtz native
typedef __attribute__((ext_vector_type(16))) float    f32x16;
typedef __attribute__((ext_vector_type(4)))  float    f32x4;
typedef __attribute__((ext_vector_type(8)))  short    short8;

static __device__ __forceinline__ unsigned short f2bf(float f) {
    union { float f; unsigned u; } v; v.f = f;
    unsigned r = v.u + 0x7fffu + ((v.u >> 16) & 1u);
    return (unsigned short)(r >> 16);
}

__global__ __launch_bounds__(384, 4) void mace_all(
    const float* __restrict__ irreps_x,
    const int*   __restrict__ atomic_numbers,
    const float* __restrict__ w_fc1,
    const float* __restrict__ b_fc1,
    const float* __restrict__ U3,
    const float* __restrict__ W3,
    const float* __restrict__ U2,
    const float* __restrict__ W2,
    const float* __restrict__ U1,
    const float* __restrict__ W1,
    const float* __restrict__ w_lin,
    const float* __restrict__ w_fc2,
    const float* __restrict__ b_fc2,
    float* __restrict__ out)
{
    __shared__ float xvL[1152];                        // [2][9][64] f32, 4608B
    __shared__ __align__(16) unsigned char region[47616];
    _Float16* const o2L       = (_Float16*)region;               // [2][96][68] f16 (main)
    float* const o1L          = (float*)region;                  // 4608B
    unsigned short* const XfA = (unsigned short*)(region + 4608);  // [32][200]
    unsigned short* const WfA = (unsigned short*)(region + 17408); // [64][200]
    float* const yL           = (float*)(region + 43008);          // 4608B

    const int t  = threadIdx.x;
    const int n0 = blockIdx.x * 2;
    const int w  = t >> 6;          // 0..5
    const int l  = t & 63;
    const int kg = l >> 4;          // 16x16x32 bf16 linears
    const int hf = l >> 5;          // 32x32x16 f16 main GEMM
    const int c32 = l & 31;

    // ---------- so3_linear machinery (bf16 16x16x32) ----------
    auto fill_Xf = [&](auto srcf) {
        for (int i = t; i < 32 * 96; i += 384) {
            int rr = i / 96, k = (i % 96) * 2;
            int lh = k >> 6, c = k & 63;
            float v0 = 0.f, v1 = 0.f;
            if (rr < 18) {
                int at = rr / 9, m = rr % 9;
                int lm = (m >= 4) ? 2 : (m >= 1 ? 1 : 0);
                if (lh == lm) { v0 = srcf(at, m, c); v1 = srcf(at, m, c + 1); }
            }
            unsigned pk = (unsigned)f2bf(v0) | ((unsigned)f2bf(v1) << 16);
            *(unsigned*)(XfA + rr * 200 + k) = pk;
        }
    };
    auto fill_Wf = [&](const float* wmat) {
        for (int i = t; i < 64 * 96; i += 384) {
            int d = i / 96, k = (i % 96) * 2;
            int lh = k >> 6, c = k & 63;
            const float* wp = wmat + lh * 4096 + d * 64 + c;
            unsigned pk = (unsigned)f2bf(wp[0]) | ((unsigned)f2bf(wp[1]) << 16);
            *(unsigned*)(WfA + d * 200 + k) = pk;
        }
    };
    auto run_linear = [&](const float* bias, float* dst, bool to_global) {
        for (int tile = w; tile < 8; tile += 6) {
            int rt = tile >> 2, ct = tile & 3;
            int row = rt * 16 + (l & 15);
            int col = ct * 16 + (l & 15);
            const unsigned short* ab = XfA + row * 200 + kg * 8;
            const unsigned short* bb = WfA + col * 200 + kg * 8;
            f32x4 acc0 = {0,0,0,0}, acc1 = {0,0,0,0};
            #pragma unroll
            for (int kt = 0; kt < 6; kt += 2) {
                short8 A0 = *(const short8*)(ab + kt * 32);
                short8 A1 = *(const short8*)(ab + (kt + 1) * 32);
                short8 B0 = *(const short8*)(bb + kt * 32);
                short8 B1 = *(const short8*)(bb + (kt + 1) * 32);
                acc0 = __builtin_amdgcn_mfma_f32_16x16x32_bf16(A0, B0, acc0, 0, 0, 0);
                acc1 = __builtin_amdgcn_mfma_f32_16x16x32_bf16(A1, B1, acc1, 0, 0, 0);
            }
            f32x4 acc = acc0 + acc1;
            #pragma unroll
            for (int r = 0; r < 4; ++r) {
                int rr = rt * 16 + kg * 4 + r;
                if (rr < 18) {
                    int at = rr / 9, m = rr % 9;
                    float v = acc[r];
                    if (bias && m == 0) v += bias[col];
                    if (to_global) dst[(n0 + at) * 576 + m * 64 + col] = v;
                    else           dst[at * 576 + m * 64 + col] = v;
                }
            }
        }
    };

    // ---------- fc1 ----------
    fill_Xf([&](int at, int m, int c) { return irreps_x[(n0 + at) * 576 + m * 64 + c]; });
    fill_Wf(w_fc1);
    __syncthreads();
    run_linear(b_fc1, xvL, false);
    __syncthreads();

    // ---------- main GEMM: wave = (atom, n-tile), raw U3/U2 B-frags ----------
    {
        const int at = w / 3, ng = w % 3;
        const int an = atomic_numbers[n0 + at];
        const float* xa  = xvL + at * 576;
        const float* W3r = W3 + an * 1024;
        const float* W2r = W2 + an * 256;

        // A-frags: s3f[mt][i][j] = x_i(c) * w3_p(c),  p = hf*8+j, c = mt*32+c32
        f16x8 s3f[2][9];
        #pragma unroll
        for (int mt = 0; mt < 2; ++mt) {
            const int c = mt * 32 + c32;
            f16x8 w3h;
            #pragma unroll
            for (int j = 0; j < 8; ++j)
                w3h[j] = (_Float16)W3r[(hf * 8 + j) * 64 + c];
            #pragma unroll
            for (int i = 0; i < 9; ++i) {
                _Float16 xi = (_Float16)xa[i * 64 + c];
                f16x8 xi8 = {xi, xi, xi, xi, xi, xi, xi, xi};
                s3f[mt][i] = w3h * xi8;
            }
        }

        const int oa  = ng * 32 + c32;
        const int oaL = (oa > 80) ? 80 : oa;           // clamp: cols 81..95 garbage, never stored
        const float* Bb = U3 + oaL * 1296 + hf * 8;

        f32x16 acc0 = {0.f}, acc1 = {0.f};
        for (int b = 0; b < 9; ++b) {
            _Float16 h0 = (_Float16)xa[b * 64 + c32];
            _Float16 h1 = (_Float16)xa[b * 64 + 32 + c32];
            f16x8 xb0 = {h0, h0, h0, h0, h0, h0, h0, h0};
            f16x8 xb1 = {h1, h1, h1, h1, h1, h1, h1, h1};
            const float* Bp = Bb + b * 144;
            #pragma unroll
            for (int ksub = 0; ksub < 9; ++ksub) {
                float4 f0 = *(const float4*)(Bp + ksub * 16);
                float4 f1 = *(const float4*)(Bp + ksub * 16 + 4);
                union { hf16x2 h2[4]; f16x8 v; } u;
                u.h2[0] = __builtin_amdgcn_cvt_pkrtz(f0.x, f0.y);
                u.h2[1] = __builtin_amdgcn_cvt_pkrtz(f0.z, f0.w);
                u.h2[2] = __builtin_amdgcn_cvt_pkrtz(f1.x, f1.y);
                u.h2[3] = __builtin_amdgcn_cvt_pkrtz(f1.z, f1.w);
                acc0 = __builtin_amdgcn_mfma_f32_32x32x16_f16(s3f[0][ksub] * xb0, u.v, acc0, 0, 0, 0);
                acc1 = __builtin_amdgcn_mfma_f32_32x32x16_f16(s3f[1][ksub] * xb1, u.v, acc1, 0, 0, 0);
            }
        }
        // U2 tail: 3 k-steps, guarded scalar loads (A zeros cancel ip2>=36)
        const float* U2r = U2 + oaL * 36;
        #pragma unroll
        for (int ks2 = 0; ks2 < 3; ++ks2) {
            f16x8 a0, a1, B;
            #pragma unroll
            for (int j = 0; j < 8; ++j) {
                int ip2 = ks2 * 16 + hf * 8 + j;
                int ii = ip2 >> 2, pp = ip2 & 3;
                float f0 = 0.f, f1 = 0.f, bv = 0.f;
                if (ii < 9) {
                    f0 = xa[ii * 64 + c32]      * W2r[pp * 64 + c32];
                    f1 = xa[ii * 64 + 32 + c32] * W2r[pp * 64 + 32 + c32];
                    bv = U2r[ip2];
                }
                a0[j] = (_Float16)f0; a1[j] = (_Float16)f1; B[j] = (_Float16)bv;
            }
            acc0 = __builtin_amdgcn_mfma_f32_32x32x16_f16(a0, B, acc0, 0, 0, 0);
            acc1 = __builtin_amdgcn_mfma_f32_32x32x16_f16(a1, B, acc1, 0, 0, 0);
        }

        // epilogue: D rows = c, cols = oa; row = (reg&3)+8*(reg>>2)+4*hf
        _Float16* o2row = o2L + (at * 96 + oa) * 68;
        #pragma unroll
        for (int q = 0; q < 4; ++q) {
            int c0 = q * 8 + hf * 4;
            f16x4 v0 = {(_Float16)acc0[q*4+0], (_Float16)acc0[q*4+1],
                        (_Float16)acc0[q*4+2], (_Float16)acc0[q*4+3]};
            f16x4 v1 = {(_Float16)acc1[q*4+0], (_Float16)acc1[q*4+1],
                        (_Float16)acc1[q*4+2], (_Float16)acc1[q*4+3]};
            *(f16x4*)(o2row + c0)      = v0;
            *(f16x4*)(o2row + 32 + c0) = v1;
        }
    }
    __syncthreads();

    // ---------- out1: sum_a out2[o,a]*x_a + U1 term ----------
    float o1v[3];
    #pragma unroll
    for (int it = 0; it < 3; ++it) {
        int i = t + it * 384;                 // < 1152
        int at2 = i / 576, r2 = i % 576, o = r2 >> 6, c = r2 & 63;
        int an2 = atomic_numbers[n0 + at2];
        float w1a = W1[an2 * 128 + c], w1b = W1[an2 * 128 + 64 + c];
        const _Float16* o2p = o2L + (at2 * 96 + o * 9) * 68 + c;
        float acc = 0.f, sa = 0.f, sb = 0.f;
        #pragma unroll
        for (int a = 0; a < 9; ++a)
            acc += (float)o2p[a * 68] * xvL[at2 * 576 + a * 64 + c];
        #pragma unroll
        for (int i2 = 0; i2 < 9; ++i2) {
            float xc = xvL[at2 * 576 + i2 * 64 + c];
            sa += U1[o * 18 + i2 * 2]     * xc;
            sb += U1[o * 18 + i2 * 2 + 1] * xc;
        }
        o1v[it] = acc + sa * w1a + sb * w1b;
    }
    __syncthreads();
    #pragma unroll
    for (int it = 0; it < 3; ++it) o1L[t + it * 384] = o1v[it];
    __syncthreads();

    // ---------- lin ----------
    fill_Xf([&](int at, int m, int c) { return o1L[at * 576 + m * 64 + c]; });
    fill_Wf(w_lin);
    __syncthreads();
    run_linear(nullptr, yL, false);
    __syncthreads();

    // ---------- fc2 -> global ----------
    fill_Xf([&](int at, int m, int c) { return yL[at * 576 + m * 64 + c]; });
    fill_Wf(w_fc2);
    __syncthreads();
    run_linear(b_fc2, out, true);
}

extern "C" void kernel_launch(void* const* d_in, const int* in_sizes, int n_in,
                              void* d_out, int out_size, void* d_ws, size_t ws_size,
                              hipStream_t stream) {
    const float* irreps_x = (const float*)d_in[0];
    const int*   anum     = (const int*)d_in[1];
    const float* w_fc1    = (const float*)d_in[2];
    const float* b_fc1    = (const float*)d_in[3];
    const float* U3       = (const float*)d_in[4];
    const float* W3       = (const float*)d_in[5];
    const float* U2       = (const float*)d_in[6];
    const float* W2       = (const float*)d_in[7];
    const float* U1       = (const float*)d_in[8];
    const float* W1       = (const float*)d_in[9];
    const float* w_lin    = (const float*)d_in[10];
    const float* w_fc2    = (const float*)d_in[11];
    const float* b_fc2    = (const float*)d_in[12];
    float* out = (float*)d_out;

    mace_all<<<512, 384, 0, stream>>>(irreps_x, anum, w_fc1, b_fc1, U3, W3,
                                      U2, W2, U1, W1, w_lin, w_fc2, b_fc2, out);
}

// Round 6
// 140.755 us; speedup vs baseline: 1.3555x; 1.3555x over previous
//
#include <hip/hip_runtime.h>

// MACE body-3, round 6: prep kernel packs U3(+U2 tail) into coalesced f16
// B-fragments (258KB, L2-resident); main = 2 atoms/block, 384 thr, 512 blocks.
// Main GEMM per atom: M=64(c) N=96(oa) K=1344, v_mfma_f32_32x32x16_f16,
// x_b folded into A via per-lane packed f16 mul.

typedef __attribute__((ext_vector_type(8)))  _Float16 f16x8;
typedef __attribute__((ext_vector_type(4)))  _Float16 f16x4;
typedef __attribute__((ext_vector_type(16))) float    f32x16;
typedef __attribute__((ext_vector_type(4)))  float    f32x4;
typedef __attribute__((ext_vector_type(8)))  short    short8;

static __device__ __forceinline__ unsigned short f2bf(float f) {
    union { float f; unsigned u; } v; v.f = f;
    unsigned r = v.u + 0x7fffu + ((v.u >> 16) & 1u);
    return (unsigned short)(r >> 16);
}

// ---- prep: U3 (+U2 tail) -> fp16 B-fragments for 32x32x16 MFMA ----
// frag idx = (ks*3 + nt)*64 + lane ; lane: col oa = nt*32+(l&31),
// k-elems = 8 f16 at k = ks*16 + (l>>5)*8 + j.  Size 84*3*64*16B = 258048 B.
__global__ void prep_u3w(const float* __restrict__ U3, const float* __restrict__ U2,
                         _Float16* __restrict__ U3w)
{
    int idx = blockIdx.x * 256 + threadIdx.x;   // 63*256 = 16128 exactly
    int ks = idx / 192, r = idx % 192;
    int nt = r >> 6, l = r & 63;
    int oa = nt * 32 + (l & 31), half = l >> 5;
    f16x8 v;
    if (ks < 81) {
        int b = ks / 9, ksub = ks % 9, ip0 = ksub * 16 + half * 8;
        #pragma unroll
        for (int j = 0; j < 8; ++j) {
            float f = (oa < 81) ? U3[(oa * 9 + b) * 144 + ip0 + j] : 0.f;
            v[j] = (_Float16)f;
        }
    } else {
        int ip0 = (ks - 81) * 16 + half * 8;
        #pragma unroll
        for (int j = 0; j < 8; ++j) {
            int ip2 = ip0 + j;
            float f = (oa < 81 && ip2 < 36) ? U2[oa * 36 + ip2] : 0.f;
            v[j] = (_Float16)f;
        }
    }
    ((f16x8*)U3w)[idx] = v;
}

__global__ __launch_bounds__(384, 3) void mace_main(
    const float* __restrict__ irreps_x,
    const int*   __restrict__ atomic_numbers,
    const float* __restrict__ w_fc1,
    const float* __restrict__ b_fc1,
    const float* __restrict__ W3,
    const float* __restrict__ W2,
    const float* __restrict__ U1,
    const float* __restrict__ W1,
    const float* __restrict__ w_lin,
    const float* __restrict__ w_fc2,
    const float* __restrict__ b_fc2,
    const _Float16* __restrict__ U3w,
    float* __restrict__ out)
{
    __shared__ float xvL[1152];                        // [2][9][64] f32, 4608B
    __shared__ __align__(16) unsigned char region[47616];
    _Float16* const o2L       = (_Float16*)region;               // [2][96][68] f16 (main)
    float* const o1L          = (float*)region;                  // 4608B
    unsigned short* const XfA = (unsigned short*)(region + 4608);  // [32][200]
    unsigned short* const WfA = (unsigned short*)(region + 17408); // [64][200]
    float* const yL           = (float*)(region + 43008);          // 4608B

    const int t  = threadIdx.x;
    const int n0 = blockIdx.x * 2;
    const int w  = t >> 6;          // 0..5
    const int l  = t & 63;
    const int kg = l >> 4;          // 16x16x32 bf16 linears
    const int hf = l >> 5;          // 32x32x16 f16 main GEMM
    const int c32 = l & 31;

    // ---------- so3_linear machinery (bf16 16x16x32) ----------
    auto fill_Xf = [&](auto srcf) {
        for (int i = t; i < 32 * 96; i += 384) {
            int rr = i / 96, k = (i % 96) * 2;
            int lh = k >> 6, c = k & 63;
            float v0 = 0.f, v1 = 0.f;
            if (rr < 18) {
                int at = rr / 9, m = rr % 9;
                int lm = (m >= 4) ? 2 : (m >= 1 ? 1 : 0);
                if (lh == lm) { v0 = srcf(at, m, c); v1 = srcf(at, m, c + 1); }
            }
            unsigned pk = (unsigned)f2bf(v0) | ((unsigned)f2bf(v1) << 16);
            *(unsigned*)(XfA + rr * 200 + k) = pk;
        }
    };
    auto fill_Wf = [&](const float* wmat) {
        for (int i = t; i < 64 * 96; i += 384) {
            int d = i / 96, k = (i % 96) * 2;
            int lh = k >> 6, c = k & 63;
            const float* wp = wmat + lh * 4096 + d * 64 + c;
            unsigned pk = (unsigned)f2bf(wp[0]) | ((unsigned)f2bf(wp[1]) << 16);
            *(unsigned*)(WfA + d * 200 + k) = pk;
        }
    };
    auto run_linear = [&](const float* bias, float* dst, bool to_global) {
        for (int tile = w; tile < 8; tile += 6) {
            int rt = tile >> 2, ct = tile & 3;
            int row = rt * 16 + (l & 15);
            int col = ct * 16 + (l & 15);
            const unsigned short* ab = XfA + row * 200 + kg * 8;
            const unsigned short* bb = WfA + col * 200 + kg * 8;
            f32x4 acc0 = {0,0,0,0}, acc1 = {0,0,0,0};
            #pragma unroll
            for (int kt = 0; kt < 6; kt += 2) {
                short8 A0 = *(const short8*)(ab + kt * 32);
                short8 A1 = *(const short8*)(ab + (kt + 1) * 32);
                short8 B0 = *(const short8*)(bb + kt * 32);
                short8 B1 = *(const short8*)(bb + (kt + 1) * 32);
                acc0 = __builtin_amdgcn_mfma_f32_16x16x32_bf16(A0, B0, acc0, 0, 0, 0);
                acc1 = __builtin_amdgcn_mfma_f32_16x16x32_bf16(A1, B1, acc1, 0, 0, 0);
            }
            f32x4 acc = acc0 + acc1;
            #pragma unroll
            for (int r = 0; r < 4; ++r) {
                int rr = rt * 16 + kg * 4 + r;
                if (rr < 18) {
                    int at = rr / 9, m = rr % 9;
                    float v = acc[r];
                    if (bias && m == 0) v += bias[col];
                    if (to_global) dst[(n0 + at) * 576 + m * 64 + col] = v;
                    else           dst[at * 576 + m * 64 + col] = v;
                }
            }
        }
    };

    // ---------- fc1 ----------
    fill_Xf([&](int at, int m, int c) { return irreps_x[(n0 + at) * 576 + m * 64 + c]; });
    fill_Wf(w_fc1);
    __syncthreads();
    run_linear(b_fc1, xvL, false);
    __syncthreads();

    // ---------- main GEMM: wave = (atom, n-tile), packed U3w B-frags ----------
    {
        const int at = w / 3, ng = w % 3;
        const int an = atomic_numbers[n0 + at];
        const float* xa  = xvL + at * 576;
        const float* W3r = W3 + an * 1024;
        const float* W2r = W2 + an * 256;

        // A-frags: s3f[mt][i][j] = x_i(c) * w3_p(c),  p = hf*8+j, c = mt*32+c32
        f16x8 s3f[2][9];
        #pragma unroll
        for (int mt = 0; mt < 2; ++mt) {
            const int c = mt * 32 + c32;
            f16x8 w3h;
            #pragma unroll
            for (int j = 0; j < 8; ++j)
                w3h[j] = (_Float16)W3r[(hf * 8 + j) * 64 + c];
            #pragma unroll
            for (int i = 0; i < 9; ++i) {
                _Float16 xi = (_Float16)xa[i * 64 + c];
                f16x8 xi8 = {xi, xi, xi, xi, xi, xi, xi, xi};
                s3f[mt][i] = w3h * xi8;
            }
        }

        f32x16 acc0 = {0.f}, acc1 = {0.f};
        const f16x8* Bp = (const f16x8*)U3w + ng * 64 + l;
        for (int b = 0; b < 9; ++b) {
            _Float16 h0 = (_Float16)xa[b * 64 + c32];
            _Float16 h1 = (_Float16)xa[b * 64 + 32 + c32];
            f16x8 xb0 = {h0, h0, h0, h0, h0, h0, h0, h0};
            f16x8 xb1 = {h1, h1, h1, h1, h1, h1, h1, h1};
            const f16x8* Bb = Bp + b * 9 * 192;
            #pragma unroll
            for (int ksub = 0; ksub < 9; ++ksub) {
                f16x8 B = Bb[ksub * 192];
                acc0 = __builtin_amdgcn_mfma_f32_32x32x16_f16(s3f[0][ksub] * xb0, B, acc0, 0, 0, 0);
                acc1 = __builtin_amdgcn_mfma_f32_32x32x16_f16(s3f[1][ksub] * xb1, B, acc1, 0, 0, 0);
            }
        }
        // U2 tail: 3 k-steps (B pre-packed/zero-padded; A guarded)
        #pragma unroll
        for (int ks2 = 0; ks2 < 3; ++ks2) {
            f16x8 a0, a1;
            #pragma unroll
            for (int j = 0; j < 8; ++j) {
                int ip2 = ks2 * 16 + hf * 8 + j;
                int ii = ip2 >> 2, pp = ip2 & 3;
                float f0 = 0.f, f1 = 0.f;
                if (ii < 9) {
                    f0 = xa[ii * 64 + c32]      * W2r[pp * 64 + c32];
                    f1 = xa[ii * 64 + 32 + c32] * W2r[pp * 64 + 32 + c32];
                }
                a0[j] = (_Float16)f0; a1[j] = (_Float16)f1;
            }
            f16x8 B = Bp[(81 + ks2) * 192];
            acc0 = __builtin_amdgcn_mfma_f32_32x32x16_f16(a0, B, acc0, 0, 0, 0);
            acc1 = __builtin_amdgcn_mfma_f32_32x32x16_f16(a1, B, acc1, 0, 0, 0);
        }

        // epilogue: D rows = c, cols = oa; row = (reg&3)+8*(reg>>2)+4*hf
        const int oa = ng * 32 + c32;
        _Float16* o2row = o2L + (at * 96 + oa) * 68;
        #pragma unroll
        for (int q = 0; q < 4; ++q) {
            int c0 = q * 8 + hf * 4;
            f16x4 v0 = {(_Float16)acc0[q*4+0], (_Float16)acc0[q*4+1],
                        (_Float16)acc0[q*4+2], (_Float16)acc0[q*4+3]};
            f16x4 v1 = {(_Float16)acc1[q*4+0], (_Float16)acc1[q*4+1],
                        (_Float16)acc1[q*4+2], (_Float16)acc1[q*4+3]};
            *(f16x4*)(o2row + c0)      = v0;
            *(f16x4*)(o2row + 32 + c0) = v1;
        }
    }
    __syncthreads();

    // ---------- out1: sum_a out2[o,a]*x_a + U1 term ----------
    float o1v[3];
    #pragma unroll
    for (int it = 0; it < 3; ++it) {
        int i = t + it * 384;                 // < 1152
        int at2 = i / 576, r2 = i % 576, o = r2 >> 6, c = r2 & 63;
        int an2 = atomic_numbers[n0 + at2];
        float w1a = W1[an2 * 128 + c], w1b = W1[an2 * 128 + 64 + c];
        const _Float16* o2p = o2L + (at2 * 96 + o * 9) * 68 + c;
        float acc = 0.f, sa = 0.f, sb = 0.f;
        #pragma unroll
        for (int a = 0; a < 9; ++a)
            acc += (float)o2p[a * 68] * xvL[at2 * 576 + a * 64 + c];
        #pragma unroll
        for (int i2 = 0; i2 < 9; ++i2) {
            float xc = xvL[at2 * 576 + i2 * 64 + c];
            sa += U1[o * 18 + i2 * 2]     * xc;
            sb += U1[o * 18 + i2 * 2 + 1] * xc;
        }
        o1v[it] = acc + sa * w1a + sb * w1b;
    }
    __syncthreads();
    #pragma unroll
    for (int it = 0; it < 3; ++it) o1L[t + it * 384] = o1v[it];
    __syncthreads();

    // ---------- lin ----------
    fill_Xf([&](int at, int m, int c) { return o1L[at * 576 + m * 64 + c]; });
    fill_Wf(w_lin);
    __syncthreads();
    run_linear(nullptr, yL, false);
    __syncthreads();

    // ---------- fc2 -> global ----------
    fill_Xf([&](int at, int m, int c) { return yL[at * 576 + m * 64 + c]; });
    fill_Wf(w_fc2);
    __syncthreads();
    run_linear(b_fc2, out, true);
}

extern "C" void kernel_launch(void* const* d_in, const int* in_sizes, int n_in,
                              void* d_out, int out_size, void* d_ws, size_t ws_size,
                              hipStream_t stream) {
    const float* irreps_x = (const float*)d_in[0];
    const int*   anum     = (const int*)d_in[1];
    const float* w_fc1    = (const float*)d_in[2];
    const float* b_fc1    = (const float*)d_in[3];
    const float* U3       = (const float*)d_in[4];
    const float* W3       = (const float*)d_in[5];
    const float* U2       = (const float*)d_in[6];
    const float* W2       = (const float*)d_in[7];
    const float* U1       = (const float*)d_in[8];
    const float* W1       = (const float*)d_in[9];
    const float* w_lin    = (const float*)d_in[10];
    const float* w_fc2    = (const float*)d_in[11];
    const float* b_fc2    = (const float*)d_in[12];
    float* out = (float*)d_out;

    _Float16* U3w = (_Float16*)d_ws;   // 258048 B needed

    prep_u3w<<<63, 256, 0, stream>>>(U3, U2, U3w);
    mace_main<<<512, 384, 0, stream>>>(irreps_x, anum, w_fc1, b_fc1, W3, W2,
                                       U1, W1, w_lin, w_fc2, b_fc2, U3w, out);
}